// Round 9
// baseline (250.719 us; speedup 1.0000x reference)
//
#include <hip/hip_runtime.h>
#include <cstdint>
#include <cmath>

#define B_ 8
#define S_ 1024
#define D_ 768
#define H_ 12
#define HD_ 64

typedef __bf16 bf16;
typedef __attribute__((ext_vector_type(8))) __bf16 bf16x8;
typedef __attribute__((ext_vector_type(4))) float floatx4;

typedef const __attribute__((address_space(1))) unsigned int* gas_ptr;
typedef __attribute__((address_space(3))) unsigned int* las_ptr;

// async global->LDS, 16B per lane. LDS dest must be wave-uniform base + lane*16.
__device__ __forceinline__ void async_ld16(const void* g, void* l) {
    gas_ptr gp = (gas_ptr)(uintptr_t)g;
    las_ptr lp = (las_ptr)(unsigned)(uintptr_t)l;
    __builtin_amdgcn_global_load_lds(gp, lp, 16, 0, 0);
}

// ---------------- tiled transpose-convert body: in[K][N] f32 -> out[N][K] bf16
__device__ __forceinline__ void transpose_dev(const float* __restrict__ in,
                                              bf16* __restrict__ out,
                                              int N, int K, int n0, int k0,
                                              bf16 (*tile)[66], int tid) {
#pragma unroll
    for (int r = 0; r < 4; r++) {
        int idx = r * 256 + tid;
        int row = idx >> 4;
        int c0  = (idx & 15) * 4;
        float4 v = *(const float4*)(in + (size_t)(k0 + row) * N + n0 + c0);
        tile[c0 + 0][row] = (bf16)v.x;
        tile[c0 + 1][row] = (bf16)v.y;
        tile[c0 + 2][row] = (bf16)v.z;
        tile[c0 + 3][row] = (bf16)v.w;
    }
    __syncthreads();
#pragma unroll
    for (int r = 0; r < 2; r++) {
        int idx = r * 256 + tid;
        int orow = idx >> 3;
        int kk   = (idx & 7) * 8;
        union { bf16x8 v; bf16 e[8]; } u;
#pragma unroll
        for (int j = 0; j < 8; j++) u.e[j] = tile[orow][kk + j];
        *(bf16x8*)(out + (size_t)(n0 + orow) * K + k0 + kk) = u.v;
    }
}

// ---------------- fused prep: x f32->bf16 (blocks 0..6143), w_qkv^T (6144..6575),
// w_proj^T (6576..6719)
__global__ __launch_bounds__(256) void prep_all(
    const float* __restrict__ x, const float* __restrict__ w_qkv,
    const float* __restrict__ w_proj,
    bf16* __restrict__ xb, bf16* __restrict__ wqkvt, bf16* __restrict__ wprojt)
{
    __shared__ bf16 tile[64][66];
    const int blk = blockIdx.x, tid = threadIdx.x;
    if (blk < 6144) {
        int i = (blk * 256 + tid) * 4;
        float4 v = *(const float4*)(x + i);
        xb[i]     = (bf16)v.x;
        xb[i + 1] = (bf16)v.y;
        xb[i + 2] = (bf16)v.z;
        xb[i + 3] = (bf16)v.w;
    } else if (blk < 6576) {
        int t = blk - 6144;
        transpose_dev(w_qkv, wqkvt, 2304, 768, (t % 36) * 64, (t / 36) * 64, tile, tid);
    } else {
        int t = blk - 6576;
        transpose_dev(w_proj, wprojt, 768, 768, (t % 12) * 64, (t / 12) * 64, tile, tid);
    }
}

// ---------------- transpose V: vbuf[b][s][768] (head dims in d'-order) -> vt[b][h][d][1024],
// keys PERMUTED for the PV B-operand: within each 32-key group, permuted position kp
// (g=kp>>3, j=kp&7) holds true key  j<4 ? 4g+j : 16+4g+(j-4).
// vbuf memory position p within a head holds true dim dt = (p>>2) + 16*(p&3).
__global__ void transpose_v(const bf16* __restrict__ vbuf, bf16* __restrict__ vt) {
    __shared__ bf16 tile[64][66];     // [true d][key true order]
    const int tid = threadIdx.x;
    const int kt = blockIdx.x, h = blockIdx.y, b = blockIdx.z;
    const bf16* src = vbuf + ((size_t)b * S_ + (size_t)kt * 64) * D_ + h * 64;
#pragma unroll
    for (int r = 0; r < 2; r++) {
        int idx = r * 256 + tid;
        int kr = idx >> 3;
        int d0 = (idx & 7) * 8;
        bf16x8 v = *(const bf16x8*)(src + (size_t)kr * D_ + d0);
#pragma unroll
        for (int j = 0; j < 8; j++) {
            int p  = d0 + j;
            int dt = (p >> 2) + 16 * (p & 3);   // undo d'-permutation
            tile[dt][kr] = v[j];
        }
    }
    __syncthreads();
    bf16* dst = vt + ((size_t)(b * H_ + h) * 64) * 1024 + kt * 64;
#pragma unroll
    for (int r = 0; r < 2; r++) {
        int idx = r * 256 + tid;
        int dr = idx >> 3;
        int k0 = (idx & 7) * 8;
        union { bf16x8 v; bf16 e[8]; } u;
#pragma unroll
        for (int j = 0; j < 8; j++) {
            int kp  = k0 + j;
            int grp = kp & 32;
            int w32 = kp & 31;
            int gg  = w32 >> 3;
            int jj  = w32 & 7;
            int tk  = grp + ((jj < 4) ? (4 * gg + jj) : (16 + 4 * gg + jj - 4));
            u.e[j] = tile[dr][tk];
        }
        *(bf16x8*)(dst + (size_t)dr * 1024 + k0) = u.v;
    }
}

// ---------------- QKV GEMM: [8192][768] x [2304][768]^T + bias -> qpack/kpack/vbuf
// qpack/kpack: [b][h][s][64] with head dims in d'-order, d' = 4*(col&15) + colsub
// (Q scaled by 0.125). vbuf: [b*s][768], heads in d'-order. Wave covers exactly one
// head (64 cols) -> wave-uniform branch, b64 packed stores.
__global__ __launch_bounds__(256, 2) void gemm_qkv(
    const bf16* __restrict__ A, const bf16* __restrict__ Bt,
    const float* __restrict__ bias,
    bf16* __restrict__ qpack, bf16* __restrict__ kpack, bf16* __restrict__ vbuf)
{
    __shared__ __align__(16) bf16 As[128 * 32];
    __shared__ __align__(16) bf16 Bs[128 * 32];
    const int N = 2304, K = 768;

    const int tid  = threadIdx.x;
    const int lane = tid & 63;
    const int w    = tid >> 6;
    const int wm   = (w >> 1) * 64;
    const int wn   = (w & 1) * 64;
    const long m0  = (long)blockIdx.y * 128;
    const long n0  = (long)blockIdx.x * 128;
    const int c    = lane & 15;
    const int g    = lane >> 4;

    const floatx4 fzero = {0.f, 0.f, 0.f, 0.f};
    floatx4 acc[4][4];
#pragma unroll
    for (int i = 0; i < 4; i++)
#pragma unroll
        for (int j = 0; j < 4; j++) acc[i][j] = fzero;

    for (int k0 = 0; k0 < K; k0 += 32) {
        __syncthreads();
#pragma unroll
        for (int r = 0; r < 2; r++) {
            const int idx = r * 256 + tid;
            const int row = idx >> 2;
            const int kk  = (idx & 3) * 8;
            async_ld16(A  + (m0 + row) * (long)K + k0 + kk, (char*)As + idx * 16);
            async_ld16(Bt + (n0 + row) * (long)K + k0 + kk, (char*)Bs + idx * 16);
        }
        __syncthreads();

        bf16x8 af[4], bfr[4];
#pragma unroll
        for (int i = 0; i < 4; i++) {
            af[i]  = *(const bf16x8*)(As + (wm + i * 16 + c) * 32 + g * 8);
            bfr[i] = *(const bf16x8*)(Bs + (wn + i * 16 + c) * 32 + g * 8);
        }
#pragma unroll
        for (int i = 0; i < 4; i++)
#pragma unroll
            for (int j = 0; j < 4; j++)
                acc[i][j] = __builtin_amdgcn_mfma_f32_16x16x32_bf16(af[i], bfr[j], acc[i][j], 0, 0, 0);
    }

    // epilogue: wave-uniform head = (n0+wn)/64; lane c owns d' = 4c..4c+3 (b64 store)
    const int head = (int)((n0 + wn) >> 6);       // 0..35
    const int rm   = wm + g * 4;
    float bv[4];
#pragma unroll
    for (int j = 0; j < 4; j++) bv[j] = bias[(int)n0 + wn + c + 16 * j];
    const int bb    = (int)(m0 >> 10);
    const int sbase = ((int)m0 & 1023) + rm;

    if (head < 24) {
        const float sc = (head < 12) ? 0.125f : 1.0f;
        bf16* dst = ((head < 12) ? qpack : kpack)
                  + (((size_t)((bb * H_ + (head < 12 ? head : head - 12)) * 1024 + sbase)) << 6)
                  + 4 * c;
#pragma unroll
        for (int i = 0; i < 4; i++)
#pragma unroll
            for (int e = 0; e < 4; e++) {
                union { bf16 h4[4]; uint64_t u; } pk;
#pragma unroll
                for (int j = 0; j < 4; j++) pk.h4[j] = (bf16)((acc[i][j][e] + bv[j]) * sc);
                *(uint64_t*)(dst + (size_t)(i * 16 + e) * 64) = pk.u;
            }
    } else {
        bf16* dst = vbuf + ((size_t)(bb * 1024 + sbase)) * 768 + (head - 24) * 64 + 4 * c;
#pragma unroll
        for (int i = 0; i < 4; i++)
#pragma unroll
            for (int e = 0; e < 4; e++) {
                union { bf16 h4[4]; uint64_t u; } pk;
#pragma unroll
                for (int j = 0; j < 4; j++) pk.h4[j] = (bf16)(acc[i][j][e] + bv[j]);
                *(uint64_t*)(dst + (size_t)(i * 16 + e) * 768) = pk.u;
            }
    }
}

// ---------------- generic GEMM (proj): C[M][N] = A[M][K]*Bt[N][K]^T + bias
__global__ __launch_bounds__(256, 2) void gemm_bt(
    const bf16* __restrict__ A, const bf16* __restrict__ Bt,
    const float* __restrict__ bias, float* __restrict__ C,
    int M, int N, int K)
{
    __shared__ __align__(16) bf16 As[128 * 32];
    __shared__ __align__(16) bf16 Bs[128 * 32];

    const int tid  = threadIdx.x;
    const int lane = tid & 63;
    const int w    = tid >> 6;
    const int wm   = (w >> 1) * 64;
    const int wn   = (w & 1) * 64;
    const long m0  = (long)blockIdx.y * 128;
    const long n0  = (long)blockIdx.x * 128;
    const int c    = lane & 15;
    const int g    = lane >> 4;

    const floatx4 fzero = {0.f, 0.f, 0.f, 0.f};
    floatx4 acc[4][4];
#pragma unroll
    for (int i = 0; i < 4; i++)
#pragma unroll
        for (int j = 0; j < 4; j++) acc[i][j] = fzero;

    for (int k0 = 0; k0 < K; k0 += 32) {
        __syncthreads();
#pragma unroll
        for (int r = 0; r < 2; r++) {
            const int idx = r * 256 + tid;
            const int row = idx >> 2;
            const int kk  = (idx & 3) * 8;
            async_ld16(A  + (m0 + row) * (long)K + k0 + kk, (char*)As + idx * 16);
            async_ld16(Bt + (n0 + row) * (long)K + k0 + kk, (char*)Bs + idx * 16);
        }
        __syncthreads();

        bf16x8 af[4], bfr[4];
#pragma unroll
        for (int i = 0; i < 4; i++) {
            af[i]  = *(const bf16x8*)(As + (wm + i * 16 + c) * 32 + g * 8);
            bfr[i] = *(const bf16x8*)(Bs + (wn + i * 16 + c) * 32 + g * 8);
        }
#pragma unroll
        for (int i = 0; i < 4; i++)
#pragma unroll
            for (int j = 0; j < 4; j++)
                acc[i][j] = __builtin_amdgcn_mfma_f32_16x16x32_bf16(af[i], bfr[j], acc[i][j], 0, 0, 0);
    }

    const int cn = wn + c;
    const int rm = wm + g * 4;
#pragma unroll
    for (int j = 0; j < 4; j++) {
        const long gn = n0 + cn + j * 16;
        const float bv = bias[gn];
#pragma unroll
        for (int i = 0; i < 4; i++) {
            const long gm = m0 + rm + i * 16;
#pragma unroll
            for (int e = 0; e < 4; e++)
                C[(gm + e) * (long)N + gn] = acc[i][j][e] + bv;
        }
    }
}

// ---------------- fused attention v2.1: transposed-S, register-resident, TLP-scaled.
// Sᵀ = K·Qᵀ (A=K rows=keys, B=Qᵀ cols=q) → C-layout: col=lane&15=q, row=key.
// P = exp(Sᵀ) stays in VGPRs as the B-operand of Oᵀ = Vᵀ·Pᵀ (vt keys pre-permuted).
// l via ones-A MFMA. No LDS, no barriers. Q/K head dims d'-permuted identically.
// 1 wave per block; wave owns 32 q x all 1024 keys -> 3072 blocks = 12 waves/CU
// (TLP hides the per-kt L2 load latency; explicit ILP prefetch loses to the
// allocator -- R5/R6 evidence).
__global__ __launch_bounds__(64, 2) void attn_fused(
    const bf16* __restrict__ qpack, const bf16* __restrict__ kpack,
    const bf16* __restrict__ vt, bf16* __restrict__ outp)
{
    const int lane = threadIdx.x & 63;
    const int g    = lane >> 4;
    const int c    = lane & 15;

    const int id = blockIdx.x;
    const int bh = id % 96;           // same-(b,h) blocks share id mod 8 -> same XCD
    const int qt = id / 96;           // 0..31
    const int h  = bh >> 3;
    const int b  = bh & 7;
    const int q0 = qt * 32;
    const bf16* qpb = qpack + ((size_t)(b * H_ + h) * 1024) * 64;
    const bf16* kpb = kpack + ((size_t)(b * H_ + h) * 1024) * 64;
    const bf16* vtb = vt    + ((size_t)(b * H_ + h) * 64) * 1024;

    // Q as B-operand: lane holds Q[q = q0+qb*16+c][pos = g*8+j]; loop-invariant
    bf16x8 qf[2][2];
#pragma unroll
    for (int qb = 0; qb < 2; qb++)
#pragma unroll
        for (int dc = 0; dc < 2; dc++)
            qf[qb][dc] = *(const bf16x8*)(qpb + (size_t)(q0 + qb * 16 + c) * 64 + dc * 32 + g * 8);

    union { uint32_t u[4]; bf16x8 v; } onesu;
    onesu.u[0] = onesu.u[1] = onesu.u[2] = onesu.u[3] = 0x3F803F80u;  // bf16 1.0 x8
    const bf16x8 onesf = onesu.v;

    const floatx4 fzero = {0.f, 0.f, 0.f, 0.f};
    floatx4 oacc[2][4];               // [qb][db]: Oᵀ, col=q, row=d (db*16+4g+e)
    floatx4 lacc[2];                  // [qb]: every entry = l[q=c]
#pragma unroll
    for (int qb = 0; qb < 2; qb++) {
        lacc[qb] = fzero;
#pragma unroll
        for (int db = 0; db < 4; db++) oacc[qb][db] = fzero;
    }

    for (int kt = 0; kt < 32; kt++) {       // 32-key groups
        const int kgbase = kt * 32;

        // K as A-operand: lane holds K[key = kgbase+kb*16+c][pos = g*8+j]
        bf16x8 kf[2][2];
#pragma unroll
        for (int kb = 0; kb < 2; kb++)
#pragma unroll
            for (int dc = 0; dc < 2; dc++)
                kf[kb][dc] = *(const bf16x8*)(kpb + (size_t)(kgbase + kb * 16 + c) * 64 + dc * 32 + g * 8);

        // Vᵀ as A-operand: lane holds Vᵀ[d = db*16+c][key' = kgbase+g*8+j] (permuted keys)
        bf16x8 vf[4];
#pragma unroll
        for (int db = 0; db < 4; db++)
            vf[db] = *(const bf16x8*)(vtb + (size_t)(db * 16 + c) * 1024 + kgbase + g * 8);

#pragma unroll
        for (int qb = 0; qb < 2; qb++) {
            // Sᵀ for 32 keys x 16 q
            floatx4 s0 = fzero, s1 = fzero;
#pragma unroll
            for (int dc = 0; dc < 2; dc++) {
                s0 = __builtin_amdgcn_mfma_f32_16x16x32_bf16(kf[0][dc], qf[qb][dc], s0, 0, 0, 0);
                s1 = __builtin_amdgcn_mfma_f32_16x16x32_bf16(kf[1][dc], qf[qb][dc], s1, 0, 0, 0);
            }
            // P = exp(Sᵀ): lane's 8 values are exactly the PV B-operand slots
            union { bf16 e[8]; bf16x8 v; } pa;
#pragma unroll
            for (int e4 = 0; e4 < 4; e4++) {
                pa.e[e4]     = (bf16)__expf(s0[e4]);
                pa.e[e4 + 4] = (bf16)__expf(s1[e4]);
            }
            // Oᵀ += Vᵀ·Pᵀ ; l += 1·Pᵀ
            lacc[qb] = __builtin_amdgcn_mfma_f32_16x16x32_bf16(onesf, pa.v, lacc[qb], 0, 0, 0);
#pragma unroll
            for (int db = 0; db < 4; db++)
                oacc[qb][db] = __builtin_amdgcn_mfma_f32_16x16x32_bf16(vf[db], pa.v, oacc[qb][db], 0, 0, 0);
        }
    }

    // epilogue: lane holds q = q0+qb*16+c, d = db*16+4g+e; pack e-pairs -> b32 stores
#pragma unroll
    for (int qb = 0; qb < 2; qb++) {
        const float linv = 1.0f / lacc[qb][0];
        bf16* orow = outp + ((size_t)b * S_ + q0 + qb * 16 + c) * D_ + h * 64;
#pragma unroll
        for (int db = 0; db < 4; db++)
#pragma unroll
            for (int f = 0; f < 2; f++) {
                union { bf16 hh[2]; uint32_t u; } pk_;
                pk_.hh[0] = (bf16)(oacc[qb][db][2 * f]     * linv);
                pk_.hh[1] = (bf16)(oacc[qb][db][2 * f + 1] * linv);
                *(uint32_t*)(orow + db * 16 + 4 * g + 2 * f) = pk_.u;
            }
    }
}

extern "C" void kernel_launch(void* const* d_in, const int* in_sizes, int n_in,
                              void* d_out, int out_size, void* d_ws, size_t ws_size,
                              hipStream_t stream) {
    const float* x      = (const float*)d_in[0];
    const float* w_qkv  = (const float*)d_in[1];
    const float* b_qkv  = (const float*)d_in[2];
    const float* w_proj = (const float*)d_in[3];
    const float* b_proj = (const float*)d_in[4];
    float* out = (float*)d_out;

    bf16* xb     = (bf16*)d_ws;                       // [8192][768]
    bf16* wqkvt  = xb     + (size_t)8192 * 768;       // [2304][768]
    bf16* wprojt = wqkvt  + (size_t)2304 * 768;       // [768][768]
    bf16* qpack  = wprojt + (size_t)768 * 768;        // [8][12][1024][64] d'-order
    bf16* kpack  = qpack  + (size_t)96 * 1024 * 64;   // [8][12][1024][64] d'-order
    bf16* vbuf   = kpack  + (size_t)96 * 1024 * 64;   // [8192][768] d'-order heads
    bf16* vt     = vbuf   + (size_t)8192 * 768;       // [8][12][64][1024] true-d, perm keys
    bf16* attnb  = xb;                                // alias (xb dead after QKV GEMM)

    prep_all<<<6720, 256, 0, stream>>>(x, w_qkv, w_proj, xb, wqkvt, wprojt);
    gemm_qkv<<<dim3(18, 64), 256, 0, stream>>>(xb, wqkvt, b_qkv, qpack, kpack, vbuf);
    transpose_v<<<dim3(16, 12, 8), 256, 0, stream>>>(vbuf, vt);
    attn_fused<<<3072, 64, 0, stream>>>(qpack, kpack, vt, attnb);
    gemm_bt<<<dim3(6, 64), 256, 0, stream>>>(attnb, wprojt, b_proj, out, 8192, 768, 768);
}

// Round 10
// 203.630 us; speedup vs baseline: 1.2312x; 1.2312x over previous
//
#include <hip/hip_runtime.h>
#include <cstdint>
#include <cmath>

#define B_ 8
#define S_ 1024
#define D_ 768
#define H_ 12
#define HD_ 64

typedef __bf16 bf16;
typedef __attribute__((ext_vector_type(8))) __bf16 bf16x8;
typedef __attribute__((ext_vector_type(4))) float floatx4;

typedef const __attribute__((address_space(1))) unsigned int* gas_ptr;
typedef __attribute__((address_space(3))) unsigned int* las_ptr;

// async global->LDS, 16B per lane. LDS dest must be wave-uniform base + lane*16.
__device__ __forceinline__ void async_ld16(const void* g, void* l) {
    gas_ptr gp = (gas_ptr)(uintptr_t)g;
    las_ptr lp = (las_ptr)(unsigned)(uintptr_t)l;
    __builtin_amdgcn_global_load_lds(gp, lp, 16, 0, 0);
}

// ---------------- tiled transpose-convert body: in[K][N] f32 -> out[N][K] bf16
__device__ __forceinline__ void transpose_dev(const float* __restrict__ in,
                                              bf16* __restrict__ out,
                                              int N, int K, int n0, int k0,
                                              bf16 (*tile)[66], int tid) {
#pragma unroll
    for (int r = 0; r < 4; r++) {
        int idx = r * 256 + tid;
        int row = idx >> 4;
        int c0  = (idx & 15) * 4;
        float4 v = *(const float4*)(in + (size_t)(k0 + row) * N + n0 + c0);
        tile[c0 + 0][row] = (bf16)v.x;
        tile[c0 + 1][row] = (bf16)v.y;
        tile[c0 + 2][row] = (bf16)v.z;
        tile[c0 + 3][row] = (bf16)v.w;
    }
    __syncthreads();
#pragma unroll
    for (int r = 0; r < 2; r++) {
        int idx = r * 256 + tid;
        int orow = idx >> 3;
        int kk   = (idx & 7) * 8;
        union { bf16x8 v; bf16 e[8]; } u;
#pragma unroll
        for (int j = 0; j < 8; j++) u.e[j] = tile[orow][kk + j];
        *(bf16x8*)(out + (size_t)(n0 + orow) * K + k0 + kk) = u.v;
    }
}

// ---------------- fused prep: x f32->bf16 (blocks 0..6143), w_qkv^T (6144..6575),
// w_proj^T (6576..6719)
__global__ __launch_bounds__(256) void prep_all(
    const float* __restrict__ x, const float* __restrict__ w_qkv,
    const float* __restrict__ w_proj,
    bf16* __restrict__ xb, bf16* __restrict__ wqkvt, bf16* __restrict__ wprojt)
{
    __shared__ bf16 tile[64][66];
    const int blk = blockIdx.x, tid = threadIdx.x;
    if (blk < 6144) {
        int i = (blk * 256 + tid) * 4;
        float4 v = *(const float4*)(x + i);
        xb[i]     = (bf16)v.x;
        xb[i + 1] = (bf16)v.y;
        xb[i + 2] = (bf16)v.z;
        xb[i + 3] = (bf16)v.w;
    } else if (blk < 6576) {
        int t = blk - 6144;
        transpose_dev(w_qkv, wqkvt, 2304, 768, (t % 36) * 64, (t / 36) * 64, tile, tid);
    } else {
        int t = blk - 6576;
        transpose_dev(w_proj, wprojt, 768, 768, (t % 12) * 64, (t / 12) * 64, tile, tid);
    }
}

// ---------------- transpose V: vbuf[b][s][768] (head dims in d'-order) -> vt[b][h][d][1024],
// keys PERMUTED for the PV B-operand: within each 32-key group, permuted position kp
// (g=kp>>3, j=kp&7) holds true key  j<4 ? 4g+j : 16+4g+(j-4).
// vbuf memory position p within a head holds true dim dt = (p>>2) + 16*(p&3).
__global__ void transpose_v(const bf16* __restrict__ vbuf, bf16* __restrict__ vt) {
    __shared__ bf16 tile[64][66];     // [true d][key true order]
    const int tid = threadIdx.x;
    const int kt = blockIdx.x, h = blockIdx.y, b = blockIdx.z;
    const bf16* src = vbuf + ((size_t)b * S_ + (size_t)kt * 64) * D_ + h * 64;
#pragma unroll
    for (int r = 0; r < 2; r++) {
        int idx = r * 256 + tid;
        int kr = idx >> 3;
        int d0 = (idx & 7) * 8;
        bf16x8 v = *(const bf16x8*)(src + (size_t)kr * D_ + d0);
#pragma unroll
        for (int j = 0; j < 8; j++) {
            int p  = d0 + j;
            int dt = (p >> 2) + 16 * (p & 3);   // undo d'-permutation
            tile[dt][kr] = v[j];
        }
    }
    __syncthreads();
    bf16* dst = vt + ((size_t)(b * H_ + h) * 64) * 1024 + kt * 64;
#pragma unroll
    for (int r = 0; r < 2; r++) {
        int idx = r * 256 + tid;
        int dr = idx >> 3;
        int k0 = (idx & 7) * 8;
        union { bf16x8 v; bf16 e[8]; } u;
#pragma unroll
        for (int j = 0; j < 8; j++) {
            int kp  = k0 + j;
            int grp = kp & 32;
            int w32 = kp & 31;
            int gg  = w32 >> 3;
            int jj  = w32 & 7;
            int tk  = grp + ((jj < 4) ? (4 * gg + jj) : (16 + 4 * gg + jj - 4));
            u.e[j] = tile[dr][tk];
        }
        *(bf16x8*)(dst + (size_t)dr * 1024 + k0) = u.v;
    }
}

// ---------------- QKV GEMM: [8192][768] x [2304][768]^T + bias -> qpack/kpack/vbuf
// qpack/kpack: [b][h][s][64] with head dims in d'-order, d' = 4*(col&15) + colsub
// (Q scaled by 0.125). vbuf: [b*s][768], heads in d'-order. Wave covers exactly one
// head (64 cols) -> wave-uniform branch, b64 packed stores.
__global__ __launch_bounds__(256, 2) void gemm_qkv(
    const bf16* __restrict__ A, const bf16* __restrict__ Bt,
    const float* __restrict__ bias,
    bf16* __restrict__ qpack, bf16* __restrict__ kpack, bf16* __restrict__ vbuf)
{
    __shared__ __align__(16) bf16 As[128 * 32];
    __shared__ __align__(16) bf16 Bs[128 * 32];
    const int N = 2304, K = 768;

    const int tid  = threadIdx.x;
    const int lane = tid & 63;
    const int w    = tid >> 6;
    const int wm   = (w >> 1) * 64;
    const int wn   = (w & 1) * 64;
    const long m0  = (long)blockIdx.y * 128;
    const long n0  = (long)blockIdx.x * 128;
    const int c    = lane & 15;
    const int g    = lane >> 4;

    const floatx4 fzero = {0.f, 0.f, 0.f, 0.f};
    floatx4 acc[4][4];
#pragma unroll
    for (int i = 0; i < 4; i++)
#pragma unroll
        for (int j = 0; j < 4; j++) acc[i][j] = fzero;

    for (int k0 = 0; k0 < K; k0 += 32) {
        __syncthreads();
#pragma unroll
        for (int r = 0; r < 2; r++) {
            const int idx = r * 256 + tid;
            const int row = idx >> 2;
            const int kk  = (idx & 3) * 8;
            async_ld16(A  + (m0 + row) * (long)K + k0 + kk, (char*)As + idx * 16);
            async_ld16(Bt + (n0 + row) * (long)K + k0 + kk, (char*)Bs + idx * 16);
        }
        __syncthreads();

        bf16x8 af[4], bfr[4];
#pragma unroll
        for (int i = 0; i < 4; i++) {
            af[i]  = *(const bf16x8*)(As + (wm + i * 16 + c) * 32 + g * 8);
            bfr[i] = *(const bf16x8*)(Bs + (wn + i * 16 + c) * 32 + g * 8);
        }
#pragma unroll
        for (int i = 0; i < 4; i++)
#pragma unroll
            for (int j = 0; j < 4; j++)
                acc[i][j] = __builtin_amdgcn_mfma_f32_16x16x32_bf16(af[i], bfr[j], acc[i][j], 0, 0, 0);
    }

    // epilogue: wave-uniform head = (n0+wn)/64; lane c owns d' = 4c..4c+3 (b64 store)
    const int head = (int)((n0 + wn) >> 6);       // 0..35
    const int rm   = wm + g * 4;
    float bv[4];
#pragma unroll
    for (int j = 0; j < 4; j++) bv[j] = bias[(int)n0 + wn + c + 16 * j];
    const int bb    = (int)(m0 >> 10);
    const int sbase = ((int)m0 & 1023) + rm;

    if (head < 24) {
        const float sc = (head < 12) ? 0.125f : 1.0f;
        bf16* dst = ((head < 12) ? qpack : kpack)
                  + (((size_t)((bb * H_ + (head < 12 ? head : head - 12)) * 1024 + sbase)) << 6)
                  + 4 * c;
#pragma unroll
        for (int i = 0; i < 4; i++)
#pragma unroll
            for (int e = 0; e < 4; e++) {
                union { bf16 h4[4]; uint64_t u; } pk;
#pragma unroll
                for (int j = 0; j < 4; j++) pk.h4[j] = (bf16)((acc[i][j][e] + bv[j]) * sc);
                *(uint64_t*)(dst + (size_t)(i * 16 + e) * 64) = pk.u;
            }
    } else {
        bf16* dst = vbuf + ((size_t)(bb * 1024 + sbase)) * 768 + (head - 24) * 64 + 4 * c;
#pragma unroll
        for (int i = 0; i < 4; i++)
#pragma unroll
            for (int e = 0; e < 4; e++) {
                union { bf16 h4[4]; uint64_t u; } pk;
#pragma unroll
                for (int j = 0; j < 4; j++) pk.h4[j] = (bf16)(acc[i][j][e] + bv[j]);
                *(uint64_t*)(dst + (size_t)(i * 16 + e) * 768) = pk.u;
            }
    }
}

// ---------------- generic GEMM (proj): C[M][N] = A[M][K]*Bt[N][K]^T + bias
__global__ __launch_bounds__(256, 2) void gemm_bt(
    const bf16* __restrict__ A, const bf16* __restrict__ Bt,
    const float* __restrict__ bias, float* __restrict__ C,
    int M, int N, int K)
{
    __shared__ __align__(16) bf16 As[128 * 32];
    __shared__ __align__(16) bf16 Bs[128 * 32];

    const int tid  = threadIdx.x;
    const int lane = tid & 63;
    const int w    = tid >> 6;
    const int wm   = (w >> 1) * 64;
    const int wn   = (w & 1) * 64;
    const long m0  = (long)blockIdx.y * 128;
    const long n0  = (long)blockIdx.x * 128;
    const int c    = lane & 15;
    const int g    = lane >> 4;

    const floatx4 fzero = {0.f, 0.f, 0.f, 0.f};
    floatx4 acc[4][4];
#pragma unroll
    for (int i = 0; i < 4; i++)
#pragma unroll
        for (int j = 0; j < 4; j++) acc[i][j] = fzero;

    for (int k0 = 0; k0 < K; k0 += 32) {
        __syncthreads();
#pragma unroll
        for (int r = 0; r < 2; r++) {
            const int idx = r * 256 + tid;
            const int row = idx >> 2;
            const int kk  = (idx & 3) * 8;
            async_ld16(A  + (m0 + row) * (long)K + k0 + kk, (char*)As + idx * 16);
            async_ld16(Bt + (n0 + row) * (long)K + k0 + kk, (char*)Bs + idx * 16);
        }
        __syncthreads();

        bf16x8 af[4], bfr[4];
#pragma unroll
        for (int i = 0; i < 4; i++) {
            af[i]  = *(const bf16x8*)(As + (wm + i * 16 + c) * 32 + g * 8);
            bfr[i] = *(const bf16x8*)(Bs + (wn + i * 16 + c) * 32 + g * 8);
        }
#pragma unroll
        for (int i = 0; i < 4; i++)
#pragma unroll
            for (int j = 0; j < 4; j++)
                acc[i][j] = __builtin_amdgcn_mfma_f32_16x16x32_bf16(af[i], bfr[j], acc[i][j], 0, 0, 0);
    }

    const int cn = wn + c;
    const int rm = wm + g * 4;
#pragma unroll
    for (int j = 0; j < 4; j++) {
        const long gn = n0 + cn + j * 16;
        const float bv = bias[gn];
#pragma unroll
        for (int i = 0; i < 4; i++) {
            const long gm = m0 + rm + i * 16;
#pragma unroll
            for (int e = 0; e < 4; e++)
                C[(gm + e) * (long)N + gn] = acc[i][j][e] + bv;
        }
    }
}

// ---------------- fused attention v3: transposed-S register-resident epilogue-free
// P-path (R7) + LDS-shared K/V staging (m97 pattern) to cut per-CU vector-memory
// instruction pressure (R8/R9 showed ~80cyc/b128-global-load throughput bound;
// ds_read_b128 is ~12cyc). Block = 2 waves x 64 q (qb=4); 768 blocks x 128 thr.
// Per 32-key group: stage K(4KB)+V(4KB) once per block; each wave: 8 ds_read_b128
// frags, 36 MFMA, exp in regs; P never leaves VGPRs; no cross-wave reduction.
__global__ __launch_bounds__(128, 3) void attn_fused(
    const bf16* __restrict__ qpack, const bf16* __restrict__ kpack,
    const bf16* __restrict__ vt, bf16* __restrict__ outp)
{
    __shared__ __align__(16) bf16 Ks[2048];   // [dc][key][32elem]  (2 planes x 32 keys)
    __shared__ __align__(16) bf16 Vs[2048];   // [d][32key]

    const int tid  = threadIdx.x;
    const int lane = tid & 63;
    const int w    = tid >> 6;
    const int g    = lane >> 4;
    const int c    = lane & 15;

    const int id = blockIdx.x;
    const int bh = id % 96;           // same-(b,h) blocks share id mod 8 -> same XCD
    const int qt = id / 96;           // 0..7
    const int h  = bh >> 3;
    const int b  = bh & 7;
    const int q0 = qt * 128 + w * 64;
    const bf16* qpb = qpack + ((size_t)(b * H_ + h) * 1024) * 64;
    const bf16* kpb = kpack + ((size_t)(b * H_ + h) * 1024) * 64;
    const bf16* vtb = vt    + ((size_t)(b * H_ + h) * 64) * 1024;

    // Q as B-operand: lane holds Q[q = q0+qb*16+c][pos = g*8+j]; loop-invariant
    bf16x8 qf[4][2];
#pragma unroll
    for (int qb = 0; qb < 4; qb++)
#pragma unroll
        for (int dc = 0; dc < 2; dc++)
            qf[qb][dc] = *(const bf16x8*)(qpb + (size_t)(q0 + qb * 16 + c) * 64 + dc * 32 + g * 8);

    union { uint32_t u[4]; bf16x8 v; } onesu;
    onesu.u[0] = onesu.u[1] = onesu.u[2] = onesu.u[3] = 0x3F803F80u;  // bf16 1.0 x8
    const bf16x8 onesf = onesu.v;

    const floatx4 fzero = {0.f, 0.f, 0.f, 0.f};
    floatx4 oacc[4][4];               // [qb][db]: Oᵀ, col=q, row=d (db*16+4g+e)
    floatx4 lacc[4];                  // [qb]: every entry = l[q=c]
#pragma unroll
    for (int qb = 0; qb < 4; qb++) {
        lacc[qb] = fzero;
#pragma unroll
        for (int db = 0; db < 4; db++) oacc[qb][db] = fzero;
    }

    for (int kt = 0; kt < 32; kt++) {       // 32-key groups
        const int kg = kt * 32;
        __syncthreads();
        // stage K tile: 256 chunks of 16B; chunk i: dc=i>>7, key=(i>>2)&31, dch=i&3
#pragma unroll
        for (int r = 0; r < 2; r++) {
            const int i  = r * 128 + tid;
            const int dc = i >> 7, key = (i >> 2) & 31, dch = i & 3;
            async_ld16(kpb + (size_t)(kg + key) * 64 + dc * 32 + dch * 8, (char*)Ks + i * 16);
        }
        // stage V tile: chunk i: d=i>>2, kch=i&3  (vt keys pre-permuted)
#pragma unroll
        for (int r = 0; r < 2; r++) {
            const int i = r * 128 + tid;
            const int d = i >> 2, kch = i & 3;
            async_ld16(vtb + (size_t)d * 1024 + kg + kch * 8, (char*)Vs + i * 16);
        }
        __syncthreads();

        // K as A-operand: lane holds K[key = kb*16+c][pos = dc*32+g*8+j]
        bf16x8 kf[2][2];
#pragma unroll
        for (int kb = 0; kb < 2; kb++)
#pragma unroll
            for (int dc = 0; dc < 2; dc++)
                kf[kb][dc] = *(const bf16x8*)(Ks + (dc * 32 + kb * 16 + c) * 32 + g * 8);

        // Vᵀ as A-operand: lane holds Vᵀ[d = db*16+c][key' = g*8+j]
        bf16x8 vf[4];
#pragma unroll
        for (int db = 0; db < 4; db++)
            vf[db] = *(const bf16x8*)(Vs + (db * 16 + c) * 32 + g * 8);

#pragma unroll
        for (int qb = 0; qb < 4; qb++) {
            // Sᵀ for 32 keys x 16 q
            floatx4 s0 = fzero, s1 = fzero;
#pragma unroll
            for (int dc = 0; dc < 2; dc++) {
                s0 = __builtin_amdgcn_mfma_f32_16x16x32_bf16(kf[0][dc], qf[qb][dc], s0, 0, 0, 0);
                s1 = __builtin_amdgcn_mfma_f32_16x16x32_bf16(kf[1][dc], qf[qb][dc], s1, 0, 0, 0);
            }
            // P = exp(Sᵀ): lane's 8 values are exactly the PV B-operand slots
            union { bf16 e[8]; bf16x8 v; } pa;
#pragma unroll
            for (int e4 = 0; e4 < 4; e4++) {
                pa.e[e4]     = (bf16)__expf(s0[e4]);
                pa.e[e4 + 4] = (bf16)__expf(s1[e4]);
            }
            // Oᵀ += Vᵀ·Pᵀ ; l += 1·Pᵀ
            lacc[qb] = __builtin_amdgcn_mfma_f32_16x16x32_bf16(onesf, pa.v, lacc[qb], 0, 0, 0);
#pragma unroll
            for (int db = 0; db < 4; db++)
                oacc[qb][db] = __builtin_amdgcn_mfma_f32_16x16x32_bf16(vf[db], pa.v, oacc[qb][db], 0, 0, 0);
        }
    }

    // epilogue: lane holds q = q0+qb*16+c, d = db*16+4g+e; pack e-pairs -> b32 stores
#pragma unroll
    for (int qb = 0; qb < 4; qb++) {
        const float linv = 1.0f / lacc[qb][0];
        bf16* orow = outp + ((size_t)b * S_ + q0 + qb * 16 + c) * D_ + h * 64;
#pragma unroll
        for (int db = 0; db < 4; db++)
#pragma unroll
            for (int f = 0; f < 2; f++) {
                union { bf16 hh[2]; uint32_t u; } pk_;
                pk_.hh[0] = (bf16)(oacc[qb][db][2 * f]     * linv);
                pk_.hh[1] = (bf16)(oacc[qb][db][2 * f + 1] * linv);
                *(uint32_t*)(orow + db * 16 + 4 * g + 2 * f) = pk_.u;
            }
    }
}

extern "C" void kernel_launch(void* const* d_in, const int* in_sizes, int n_in,
                              void* d_out, int out_size, void* d_ws, size_t ws_size,
                              hipStream_t stream) {
    const float* x      = (const float*)d_in[0];
    const float* w_qkv  = (const float*)d_in[1];
    const float* b_qkv  = (const float*)d_in[2];
    const float* w_proj = (const float*)d_in[3];
    const float* b_proj = (const float*)d_in[4];
    float* out = (float*)d_out;

    bf16* xb     = (bf16*)d_ws;                       // [8192][768]
    bf16* wqkvt  = xb     + (size_t)8192 * 768;       // [2304][768]
    bf16* wprojt = wqkvt  + (size_t)2304 * 768;       // [768][768]
    bf16* qpack  = wprojt + (size_t)768 * 768;        // [8][12][1024][64] d'-order
    bf16* kpack  = qpack  + (size_t)96 * 1024 * 64;   // [8][12][1024][64] d'-order
    bf16* vbuf   = kpack  + (size_t)96 * 1024 * 64;   // [8192][768] d'-order heads
    bf16* vt     = vbuf   + (size_t)8192 * 768;       // [8][12][64][1024] true-d, perm keys
    bf16* attnb  = xb;                                // alias (xb dead after QKV GEMM)

    prep_all<<<6720, 256, 0, stream>>>(x, w_qkv, w_proj, xb, wqkvt, wprojt);
    gemm_qkv<<<dim3(18, 64), 256, 0, stream>>>(xb, wqkvt, b_qkv, qpack, kpack, vbuf);
    transpose_v<<<dim3(16, 12, 8), 256, 0, stream>>>(vbuf, vt);
    attn_fused<<<768, 128, 0, stream>>>(qpack, kpack, vt, attnb);
    gemm_bt<<<dim3(6, 64), 256, 0, stream>>>(attnb, wprojt, b_proj, out, 8192, 768, 768);
}